// Round 2
// baseline (456.895 us; speedup 1.0000x reference)
//
#include <hip/hip_runtime.h>

#define N_NODES 100000
#define N_EDGES 1600000
#define D_IN    128
#define D_OUT   32
#define RPB     8                       // rows per fine bucket
#define NB      (N_NODES / RPB)         // 12500 fine buckets (exact)
#define CROWS   2048                    // rows per coarse bucket
#define NCB     49                      // ceil(100000/2048)
#define FPC     (CROWS / RPB)           // 256 fine buckets per coarse
#define NSH     8                       // shards per coarse
#define CAP_A   4500                    // records per (coarse,shard) seg
#define DEPTH   48                      // LDS staging depth per bin (mean 16, +8s)
#define CAPF    200                     // records per fine bucket (mean 128, +6s)
#define GEMM_BLKS ((N_NODES + 63) / 64) // 1563
#define GRID_A  2048                    // phaseA blocks (8/CU when alone)
#define EPB_A   ((N_EDGES + GRID_A - 1) / GRID_A)   // 782
#define KPB     8                       // buckets per reduce block
#define K3_BLKS ((NB + KPB - 1) / KPB)  // 1563

typedef __attribute__((ext_vector_type(8))) short bf16x8;
typedef __attribute__((ext_vector_type(4))) float f32x4;

__device__ inline short f2bf(float f) {         // RNE float->bf16
    union { float f; unsigned u; } v; v.f = f;
    unsigned r = (v.u + 0x7FFFu + ((v.u >> 16) & 1u)) >> 16;
    return (short)r;
}
__device__ inline float bf2f(unsigned short b) {
    return __uint_as_float((unsigned)b << 16);
}

// ---------------------------------------------------------------------------
// Combined kernel: blocks [0, GEMM_BLKS) do gemm; blocks [GEMM_BLKS, +GRID_A)
// do phaseA coarse partition. Byte-identical to the verified 185.9 baseline.
// ---------------------------------------------------------------------------
union SMemGA {
    struct { short wbt[D_IN * D_OUT]; } g;                               // 8 KB
    struct { uint2 lbin[NCB][DEPTH]; int lcnt[NCB]; int gbase[NCB]; } a; // 19.2 KB
};

__global__ __launch_bounds__(256) void gemm_phaseA_kernel(
    const float* __restrict__ input, const float* __restrict__ W,
    const int* __restrict__ erow,    const int* __restrict__ ecol,
    const int* __restrict__ etime,
    unsigned short* __restrict__ h16,
    int* __restrict__ gcur,          // NCB*NSH cursors, stride 16 ints
    uint2* __restrict__ segA)
{
    __shared__ SMemGA sm;
    const int tid = threadIdx.x;

    if (blockIdx.x < GEMM_BLKS) {
        // ----------------- gemm role: h16 = bf16(relu(in @ W)) ------------
        for (int i = tid; i < D_IN * D_OUT; i += 256) {
            const int k = i >> 5, c = i & 31;
            sm.g.wbt[c * D_IN + k] = f2bf(W[i]);
        }
        __syncthreads();

        const int wave = tid >> 6;
        const int lane = tid & 63;
        const int r0   = blockIdx.x * 64 + wave * 16;
        const int c16  = lane & 15;
        const int quad = lane >> 4;

        int ra = r0 + c16;
        if (ra >= N_NODES) ra = N_NODES - 1;
        const float* arow = input + (size_t)ra * D_IN;

        f32x4 acc0 = {0.f, 0.f, 0.f, 0.f};
        f32x4 acc1 = {0.f, 0.f, 0.f, 0.f};
#pragma unroll
        for (int q = 0; q < 4; ++q) {
            const float* ap = arow + q * 32 + quad * 8;
            f32x4 a0 = *(const f32x4*)(ap);
            f32x4 a1 = *(const f32x4*)(ap + 4);
            bf16x8 af;
            af[0] = f2bf(a0.x); af[1] = f2bf(a0.y); af[2] = f2bf(a0.z); af[3] = f2bf(a0.w);
            af[4] = f2bf(a1.x); af[5] = f2bf(a1.y); af[6] = f2bf(a1.z); af[7] = f2bf(a1.w);
            bf16x8 b0 = *(const bf16x8*)(sm.g.wbt + (c16)      * D_IN + q * 32 + quad * 8);
            bf16x8 b1 = *(const bf16x8*)(sm.g.wbt + (c16 + 16) * D_IN + q * 32 + quad * 8);
            acc0 = __builtin_amdgcn_mfma_f32_16x16x32_bf16(af, b0, acc0, 0, 0, 0);
            acc1 = __builtin_amdgcn_mfma_f32_16x16x32_bf16(af, b1, acc1, 0, 0, 0);
        }
#pragma unroll
        for (int i = 0; i < 4; ++i) {
            const int rr = r0 + quad * 4 + i;
            if (rr < N_NODES) {
                h16[(size_t)rr * D_OUT + c16]      = (unsigned short)f2bf(fmaxf(acc0[i], 0.f));
                h16[(size_t)rr * D_OUT + c16 + 16] = (unsigned short)f2bf(fmaxf(acc1[i], 0.f));
            }
        }
    } else {
        // ----------------- phaseA role: coarse partition ------------------
        const int blk   = blockIdx.x - GEMM_BLKS;
        const int shard = blk & (NSH - 1);
        const int wv    = tid >> 6;
        const int ln    = tid & 63;

        if (tid < NCB) sm.a.lcnt[tid] = 0;
        __syncthreads();

        const int e_beg = blk * EPB_A;
        const int e_end = min(e_beg + EPB_A, N_EDGES);

        for (int e = e_beg + tid; e < e_end; e += 256) {
            const int row = erow[e];
            const int cb  = row >> 11;
            uint2 p;
            p.x = (unsigned)ecol[e] | ((unsigned)(row & (CROWS - 1)) << 17);
            p.y = (unsigned)etime[e];
            const int pos = atomicAdd(&sm.a.lcnt[cb], 1);
            if (pos < DEPTH) sm.a.lbin[cb][pos] = p;
            else {  // statistically never; correctness-safe direct write
                const int gp = atomicAdd(&gcur[(cb * NSH + shard) * 16], 1);
                if (gp < CAP_A) segA[(size_t)(cb * NSH + shard) * CAP_A + gp] = p;
            }
        }
        __syncthreads();

        if (tid < NCB) {
            const int c = min(sm.a.lcnt[tid], DEPTH);
            sm.a.gbase[tid] = atomicAdd(&gcur[(tid * NSH + shard) * 16], c);
        }
        __syncthreads();

        for (int bin = wv; bin < NCB; bin += 4) {
            const int c  = min(sm.a.lcnt[bin], DEPTH);
            const int gb = sm.a.gbase[bin];
            uint2* seg = segA + (size_t)(bin * NSH + shard) * CAP_A;
            for (int k = ln; k < c; k += 64)
                if (gb + k < CAP_A) seg[gb + k] = sm.a.lbin[bin][k];
        }
    }
}

// ---------------------------------------------------------------------------
// Phase B: 2 blocks per (coarse, shard) segment (784 blocks). Unchanged.
// Packs to 4-byte fine records: col(17) | rl_fine(3)<<17 | etime(12)<<20.
// ---------------------------------------------------------------------------
__global__ __launch_bounds__(256) void phaseB_kernel(
    const int* __restrict__ gcur, const uint2* __restrict__ segA,
    int* __restrict__ fcur,
    unsigned* __restrict__ spk2)
{
    __shared__ int hist[FPC];
    __shared__ int curs[FPC];

    const int tid    = threadIdx.x;
    const int seg_id = blockIdx.x >> 1;
    const int half   = blockIdx.x & 1;
    const int cb     = seg_id >> 3;
    const int shard  = seg_id & 7;
    const int ntot   = min(gcur[(cb * NSH + shard) * 16], CAP_A);
    const int nh     = (ntot + 1) >> 1;
    const int beg    = half * nh;
    const int end    = min(ntot, beg + nh);
    const uint2* seg = segA + (size_t)(cb * NSH + shard) * CAP_A;

    hist[tid] = 0;
    __syncthreads();

    for (int i = beg + tid; i < end; i += 256)
        atomicAdd(&hist[(seg[i].x >> 20) & 255], 1);
    __syncthreads();

    {
        const int h  = hist[tid];
        const int fb = cb * FPC + tid;
        curs[tid] = (h && fb < NB) ? atomicAdd(&fcur[fb], h) : 0;
    }
    __syncthreads();

    for (int i = beg + tid; i < end; i += 256) {
        const uint2 p   = seg[i];
        const unsigned crl = (p.x >> 17) & 2047u;
        const int      fl  = crl >> 3;
        const unsigned rec = (p.x & 0x1FFFFu) | ((crl & 7u) << 17) | (p.y << 20);
        const int pos = atomicAdd(&curs[fl], 1);
        if (pos < CAPF)
            spk2[(size_t)(cb * FPC + fl) * CAPF + pos] = rec;
    }
}

// ---------------------------------------------------------------------------
// Bucket reduce, v2: 1563 blocks x 8 buckets (one block-generation chip-wide,
// ~24 waves/CU). Stage all 8 record segments coalesced into LDS, then replace
// the 2-pass counting sort (+4 barriers + serial prefix) with direct
// ds_add_f32 accumulation into per-bucket acc[8][32]: lane c -> bank c
// (conflict-free), groups own disjoint buckets (no same-address collisions).
// 2 barriers per 8 buckets; epilogue store is perfectly contiguous:
// out[b0*256 + i].
// ---------------------------------------------------------------------------
__global__ __launch_bounds__(256) void bucket_reduce_kernel(
    const unsigned short* __restrict__ h16, const int* __restrict__ fcur,
    const unsigned* __restrict__ spk2, const float* __restrict__ dw1,
    const float* __restrict__ dw2, const int* __restrict__ arrive,
    const int* __restrict__ obs, float* __restrict__ out)
{
    __shared__ unsigned pk[KPB][256];     // 8 KB record staging
    __shared__ float    acc[KPB * 256];   // 8 KB: [bucket][row(3)][col(5)]

    const int tid = threadIdx.x;
    const int b0  = blockIdx.x * KPB;

    // Stage 8 segments (one bucket per 256-thread sweep, coalesced) + zero acc
    for (int i = tid; i < KPB * 256; i += 256) {
        acc[i] = 0.f;
        const int s  = i >> 8;
        const int j  = i & 255;
        const int bs = b0 + s;
        if (j < CAPF && bs < NB)
            pk[s][j] = spk2[(size_t)bs * CAPF + j];
    }
    __syncthreads();

    const int g = tid >> 5;               // group g owns bucket b0+g
    const int c = tid & 31;
    const int b = b0 + g;
    const int n = (b < NB) ? min(fcur[b], CAPF) : 0;
    float* ag = acc + g * 256;
    const unsigned* mypk = pk[g];

    int j = 0;
    for (; j + 4 <= n; j += 4) {
        const unsigned r0 = mypk[j],     r1 = mypk[j + 1];
        const unsigned r2 = mypk[j + 2], r3 = mypk[j + 3];
        const float h0 = bf2f(h16[(size_t)(r0 & 0x1FFFF) * D_OUT + c]);
        const float h1 = bf2f(h16[(size_t)(r1 & 0x1FFFF) * D_OUT + c]);
        const float h2 = bf2f(h16[(size_t)(r2 & 0x1FFFF) * D_OUT + c]);
        const float h3 = bf2f(h16[(size_t)(r3 & 0x1FFFF) * D_OUT + c]);
        atomicAdd(&ag[((r0 >> 17) & 7) * 32 + c], dw1[r0 >> 20] * h0);
        atomicAdd(&ag[((r1 >> 17) & 7) * 32 + c], dw1[r1 >> 20] * h1);
        atomicAdd(&ag[((r2 >> 17) & 7) * 32 + c], dw1[r2 >> 20] * h2);
        atomicAdd(&ag[((r3 >> 17) & 7) * 32 + c], dw1[r3 >> 20] * h3);
    }
    for (; j < n; ++j) {
        const unsigned r = mypk[j];
        const float h = bf2f(h16[(size_t)(r & 0x1FFFF) * D_OUT + c]);
        atomicAdd(&ag[((r >> 17) & 7) * 32 + c], dw1[r >> 20] * h);
    }
    __syncthreads();

    // Epilogue: out[b0*256 + i] is contiguous; 32 lanes share each arrive[r]
    const int T = 60 * obs[0];
    for (int i = tid; i < KPB * 256; i += 256) {
        const size_t flat = (size_t)b0 * 256 + i;
        if (flat < (size_t)N_NODES * D_OUT) {
            const int r = (int)(flat >> 5);
            out[flat] = acc[i] * dw2[T - arrive[r] - 1];
        }
    }
}

extern "C" void kernel_launch(void* const* d_in, const int* in_sizes, int n_in,
                              void* d_out, int out_size, void* d_ws, size_t ws_size,
                              hipStream_t stream)
{
    const float* input  = (const float*)d_in[0];
    const float* W      = (const float*)d_in[1];
    const float* dw1    = (const float*)d_in[2];
    const float* dw2    = (const float*)d_in[3];
    const int*   erow   = (const int*)d_in[4];
    const int*   ecol   = (const int*)d_in[5];
    const int*   etime  = (const int*)d_in[6];
    const int*   arrive = (const int*)d_in[7];
    const int*   obs    = (const int*)d_in[8];

    float* out = (float*)d_out;

    // Workspace layout (~31 MB); gcur and fcur contiguous for one memset
    char* p = (char*)d_ws;
    unsigned short* h16 = (unsigned short*)p;                 // 6.4 MB
    p += (size_t)N_NODES * D_OUT * 2;
    p = (char*)(((size_t)p + 255) & ~(size_t)255);
    int* gcur = (int*)p;                                      // 25 KB
    p += (size_t)NCB * NSH * 16 * 4;
    int* fcur = (int*)p;                                      // 50 KB
    p += (size_t)NB * 4;
    p = (char*)(((size_t)p + 255) & ~(size_t)255);
    uint2* segA = (uint2*)p;                                  // 14.1 MB
    p += (size_t)NCB * NSH * CAP_A * 8;
    p = (char*)(((size_t)p + 255) & ~(size_t)255);
    unsigned* spk2 = (unsigned*)p;                            // 10 MB

    hipMemsetAsync(gcur, 0, (size_t)(NCB * NSH * 16 + NB) * 4, stream);

    gemm_phaseA_kernel<<<GEMM_BLKS + GRID_A, 256, 0, stream>>>(
        input, W, erow, ecol, etime, h16, gcur, segA);
    phaseB_kernel<<<NCB * NSH * 2, 256, 0, stream>>>(gcur, segA, fcur, spk2);
    bucket_reduce_kernel<<<K3_BLKS, 256, 0, stream>>>(
        h16, fcur, spk2, dw1, dw2, arrive, obs, out);
}

// Round 3
// 189.270 us; speedup vs baseline: 2.4140x; 2.4140x over previous
//
#include <hip/hip_runtime.h>

#define N_NODES 100000
#define N_EDGES 1600000
#define D_IN    128
#define D_OUT   32
#define CROWS   2048                    // rows per coarse bucket
#define NCB     49                      // ceil(100000/2048)
#define NSH     8                       // shards per coarse
#define CAP_A   4500                    // records per (coarse,shard) seg
#define DEPTH   48                      // LDS staging depth per bin (mean 16, +8s)
#define NROWP   (NCB * CROWS)           // 100352 padded row count
#define CAP_R   64                      // records per row (mean 16, +12 sigma)
#define GEMM_BLKS ((N_NODES + 63) / 64) // 1563
#define GRID_A  2048                    // phaseA blocks
#define EPB_A   ((N_EDGES + GRID_A - 1) / GRID_A)   // 782
#define RPB3    32                      // rows per reduce block
#define K3_BLKS (N_NODES / RPB3)        // 3125 exact

typedef __attribute__((ext_vector_type(8))) short bf16x8;
typedef __attribute__((ext_vector_type(4))) float f32x4;

__device__ inline short f2bf(float f) {         // RNE float->bf16
    union { float f; unsigned u; } v; v.f = f;
    unsigned r = (v.u + 0x7FFFu + ((v.u >> 16) & 1u)) >> 16;
    return (short)r;
}

// ---------------------------------------------------------------------------
// K1: blocks [0, GEMM_BLKS) gemm; blocks [GEMM_BLKS, +GRID_A) phaseA coarse
// partition. Byte-identical to the verified 185.9 baseline.
// ---------------------------------------------------------------------------
union SMemGA {
    struct { short wbt[D_IN * D_OUT]; } g;                               // 8 KB
    struct { uint2 lbin[NCB][DEPTH]; int lcnt[NCB]; int gbase[NCB]; } a; // 19.2 KB
};

__global__ __launch_bounds__(256) void gemm_phaseA_kernel(
    const float* __restrict__ input, const float* __restrict__ W,
    const int* __restrict__ erow,    const int* __restrict__ ecol,
    const int* __restrict__ etime,
    unsigned short* __restrict__ h16,
    int* __restrict__ gcur,          // NCB*NSH cursors, stride 16 ints
    uint2* __restrict__ segA)
{
    __shared__ SMemGA sm;
    const int tid = threadIdx.x;

    if (blockIdx.x < GEMM_BLKS) {
        // ----------------- gemm role: h16 = bf16(relu(in @ W)) ------------
        for (int i = tid; i < D_IN * D_OUT; i += 256) {
            const int k = i >> 5, c = i & 31;
            sm.g.wbt[c * D_IN + k] = f2bf(W[i]);
        }
        __syncthreads();

        const int wave = tid >> 6;
        const int lane = tid & 63;
        const int r0   = blockIdx.x * 64 + wave * 16;
        const int c16  = lane & 15;
        const int quad = lane >> 4;

        int ra = r0 + c16;
        if (ra >= N_NODES) ra = N_NODES - 1;
        const float* arow = input + (size_t)ra * D_IN;

        f32x4 acc0 = {0.f, 0.f, 0.f, 0.f};
        f32x4 acc1 = {0.f, 0.f, 0.f, 0.f};
#pragma unroll
        for (int q = 0; q < 4; ++q) {
            const float* ap = arow + q * 32 + quad * 8;
            f32x4 a0 = *(const f32x4*)(ap);
            f32x4 a1 = *(const f32x4*)(ap + 4);
            bf16x8 af;
            af[0] = f2bf(a0.x); af[1] = f2bf(a0.y); af[2] = f2bf(a0.z); af[3] = f2bf(a0.w);
            af[4] = f2bf(a1.x); af[5] = f2bf(a1.y); af[6] = f2bf(a1.z); af[7] = f2bf(a1.w);
            bf16x8 b0 = *(const bf16x8*)(sm.g.wbt + (c16)      * D_IN + q * 32 + quad * 8);
            bf16x8 b1 = *(const bf16x8*)(sm.g.wbt + (c16 + 16) * D_IN + q * 32 + quad * 8);
            acc0 = __builtin_amdgcn_mfma_f32_16x16x32_bf16(af, b0, acc0, 0, 0, 0);
            acc1 = __builtin_amdgcn_mfma_f32_16x16x32_bf16(af, b1, acc1, 0, 0, 0);
        }
#pragma unroll
        for (int i = 0; i < 4; ++i) {
            const int rr = r0 + quad * 4 + i;
            if (rr < N_NODES) {
                h16[(size_t)rr * D_OUT + c16]      = (unsigned short)f2bf(fmaxf(acc0[i], 0.f));
                h16[(size_t)rr * D_OUT + c16 + 16] = (unsigned short)f2bf(fmaxf(acc1[i], 0.f));
            }
        }
    } else {
        // ----------------- phaseA role: coarse partition ------------------
        const int blk   = blockIdx.x - GEMM_BLKS;
        const int shard = blk & (NSH - 1);
        const int wv    = tid >> 6;
        const int ln    = tid & 63;

        if (tid < NCB) sm.a.lcnt[tid] = 0;
        __syncthreads();

        const int e_beg = blk * EPB_A;
        const int e_end = min(e_beg + EPB_A, N_EDGES);

        for (int e = e_beg + tid; e < e_end; e += 256) {
            const int row = erow[e];
            const int cb  = row >> 11;
            uint2 p;
            p.x = (unsigned)ecol[e] | ((unsigned)(row & (CROWS - 1)) << 17);
            p.y = (unsigned)etime[e];
            const int pos = atomicAdd(&sm.a.lcnt[cb], 1);
            if (pos < DEPTH) sm.a.lbin[cb][pos] = p;
            else {  // statistically never; correctness-safe direct write
                const int gp = atomicAdd(&gcur[(cb * NSH + shard) * 16], 1);
                if (gp < CAP_A) segA[(size_t)(cb * NSH + shard) * CAP_A + gp] = p;
            }
        }
        __syncthreads();

        if (tid < NCB) {
            const int c = min(sm.a.lcnt[tid], DEPTH);
            sm.a.gbase[tid] = atomicAdd(&gcur[(tid * NSH + shard) * 16], c);
        }
        __syncthreads();

        for (int bin = wv; bin < NCB; bin += 4) {
            const int c  = min(sm.a.lcnt[bin], DEPTH);
            const int gb = sm.a.gbase[bin];
            uint2* seg = segA + (size_t)(bin * NSH + shard) * CAP_A;
            for (int k = ln; k < c; k += 64)
                if (gb + k < CAP_A) seg[gb + k] = sm.a.lbin[bin][k];
        }
    }
}

// ---------------------------------------------------------------------------
// K2 (phaseB): 2 blocks per (coarse, shard) segment (784 blocks). Now sorts
// to PER-ROW segments (2048 hist bins = rows in coarse bucket), so K3 needs
// no sort at all. Record: col(17) | etime(12)<<20.
// ---------------------------------------------------------------------------
__global__ __launch_bounds__(256) void phaseB_kernel(
    const int* __restrict__ gcur, const uint2* __restrict__ segA,
    int* __restrict__ fcur,
    unsigned* __restrict__ spk2)
{
    __shared__ int hist[CROWS];          // 8 KB
    __shared__ int curs[CROWS];          // 8 KB

    const int tid    = threadIdx.x;
    const int seg_id = blockIdx.x >> 1;
    const int half   = blockIdx.x & 1;
    const int cb     = seg_id >> 3;
    const int shard  = seg_id & 7;
    const int ntot   = min(gcur[(cb * NSH + shard) * 16], CAP_A);
    const int nh     = (ntot + 1) >> 1;
    const int beg    = half * nh;
    const int end    = min(ntot, beg + nh);
    const uint2* seg = segA + (size_t)(cb * NSH + shard) * CAP_A;

    for (int t = tid; t < CROWS; t += 256) hist[t] = 0;
    __syncthreads();

    for (int i = beg + tid; i < end; i += 256)
        atomicAdd(&hist[(seg[i].x >> 17) & (CROWS - 1)], 1);
    __syncthreads();

    for (int t = tid; t < CROWS; t += 256) {
        const int h = hist[t];
        curs[t] = h ? atomicAdd(&fcur[cb * CROWS + t], h) : 0;
    }
    __syncthreads();

    for (int i = beg + tid; i < end; i += 256) {
        const uint2 p   = seg[i];
        const int   fl  = (p.x >> 17) & (CROWS - 1);
        const unsigned rec = (p.x & 0x1FFFFu) | (p.y << 20);
        const int pos = atomicAdd(&curs[fl], 1);
        if (pos < CAP_R)
            spk2[((size_t)(cb * CROWS + fl) << 6) + pos] = rec;
    }
}

// ---------------------------------------------------------------------------
// K3 (row reduce): 3125 blocks x 32 rows. No sort, no atomics, 1 barrier.
// Stage 32 row-segments (8 KB, fully coalesced uint4) into LDS (+4-word row
// pad: 16B-aligned rows, conflict-free group reads). 8-lane groups per row:
// lane li covers cols 4*li..+3 via one uint2 (bf16 hi-half unpack is a free
// AND). 8-deep unrolled gather (one 64B line per record). float4 store,
// fully coalesced per wave.
// ---------------------------------------------------------------------------
__global__ __launch_bounds__(256) void row_reduce_kernel(
    const unsigned short* __restrict__ h16, const int* __restrict__ fcur,
    const unsigned* __restrict__ spk2, const float* __restrict__ dw1,
    const float* __restrict__ dw2, const int* __restrict__ arrive,
    const int* __restrict__ obs, float* __restrict__ out)
{
    __shared__ unsigned pk[RPB3][CAP_R + 4];   // stride 68 words = 272 B
    __shared__ int ncnt[RPB3];

    const int tid = threadIdx.x;
    const int b   = blockIdx.x;

    // Coalesced stage: 512 uint4 = 8 KB (rows contiguous in spk2)
    const uint4* src = (const uint4*)(spk2 + ((size_t)b * RPB3 << 6));
#pragma unroll
    for (int i = 0; i < 2; ++i) {
        const int idx = tid + i * 256;
        const uint4 v = src[idx];
        *(uint4*)&pk[idx >> 4][(idx & 15) * 4] = v;
    }
    if (tid < RPB3) ncnt[tid] = min(fcur[b * RPB3 + tid], CAP_R);
    __syncthreads();

    const int g  = tid >> 3;             // group g owns row b*32+g
    const int li = tid & 7;              // lane covers cols 4*li..4*li+3
    const int r  = b * RPB3 + g;
    const int n  = ncnt[g];
    const unsigned short* hp = h16 + li * 4;

    float a0 = 0.f, a1 = 0.f, a2 = 0.f, a3 = 0.f;
    int j = 0;
    for (; j + 8 <= n; j += 8) {
#pragma unroll
        for (int u = 0; u < 8; ++u) {
            const unsigned rec = pk[g][j + u];
            const uint2 hv = *(const uint2*)(hp + ((size_t)(rec & 0x1FFFFu) << 5));
            const float w  = dw1[rec >> 20];
            a0 = fmaf(w, __uint_as_float(hv.x << 16),         a0);
            a1 = fmaf(w, __uint_as_float(hv.x & 0xFFFF0000u), a1);
            a2 = fmaf(w, __uint_as_float(hv.y << 16),         a2);
            a3 = fmaf(w, __uint_as_float(hv.y & 0xFFFF0000u), a3);
        }
    }
    for (; j < n; ++j) {
        const unsigned rec = pk[g][j];
        const uint2 hv = *(const uint2*)(hp + ((size_t)(rec & 0x1FFFFu) << 5));
        const float w  = dw1[rec >> 20];
        a0 = fmaf(w, __uint_as_float(hv.x << 16),         a0);
        a1 = fmaf(w, __uint_as_float(hv.x & 0xFFFF0000u), a1);
        a2 = fmaf(w, __uint_as_float(hv.y << 16),         a2);
        a3 = fmaf(w, __uint_as_float(hv.y & 0xFFFF0000u), a3);
    }

    const int T = 60 * obs[0];
    const float sdw = dw2[T - arrive[r] - 1];
    float4 o;
    o.x = a0 * sdw; o.y = a1 * sdw; o.z = a2 * sdw; o.w = a3 * sdw;
    *(float4*)(out + ((size_t)r << 5) + li * 4) = o;
}

extern "C" void kernel_launch(void* const* d_in, const int* in_sizes, int n_in,
                              void* d_out, int out_size, void* d_ws, size_t ws_size,
                              hipStream_t stream)
{
    const float* input  = (const float*)d_in[0];
    const float* W      = (const float*)d_in[1];
    const float* dw1    = (const float*)d_in[2];
    const float* dw2    = (const float*)d_in[3];
    const int*   erow   = (const int*)d_in[4];
    const int*   ecol   = (const int*)d_in[5];
    const int*   etime  = (const int*)d_in[6];
    const int*   arrive = (const int*)d_in[7];
    const int*   obs    = (const int*)d_in[8];

    float* out = (float*)d_out;

    // Workspace (~47 MB of 256 MiB): h16 | gcur | fcur | segA | spk2
    char* p = (char*)d_ws;
    unsigned short* h16 = (unsigned short*)p;                 // 6.4 MB
    p += (size_t)N_NODES * D_OUT * 2;
    p = (char*)(((size_t)p + 255) & ~(size_t)255);
    int* gcur = (int*)p;                                      // 25 KB
    p += (size_t)NCB * NSH * 16 * 4;
    int* fcur = (int*)p;                                      // 402 KB (per row)
    p += (size_t)NROWP * 4;
    p = (char*)(((size_t)p + 255) & ~(size_t)255);
    uint2* segA = (uint2*)p;                                  // 14.1 MB
    p += (size_t)NCB * NSH * CAP_A * 8;
    p = (char*)(((size_t)p + 255) & ~(size_t)255);
    unsigned* spk2 = (unsigned*)p;                            // 25.7 MB
    p += (size_t)NROWP * CAP_R * 4;

    hipMemsetAsync(gcur, 0, (size_t)(NCB * NSH * 16 + NROWP) * 4, stream);

    gemm_phaseA_kernel<<<GEMM_BLKS + GRID_A, 256, 0, stream>>>(
        input, W, erow, ecol, etime, h16, gcur, segA);
    phaseB_kernel<<<NCB * NSH * 2, 256, 0, stream>>>(gcur, segA, fcur, spk2);
    row_reduce_kernel<<<K3_BLKS, 256, 0, stream>>>(
        h16, fcur, spk2, dw1, dw2, arrive, obs, out);
}